// Round 10
// baseline (304.178 us; speedup 1.0000x reference)
//
#include <hip/hip_runtime.h>

#define HID 32
#define SEQ 512
#define WAVES_PER_BLOCK 4
#define BLOCK (WAVES_PER_BLOCK * 64)

typedef float v2f __attribute__((ext_vector_type(2)));

// ---------------------------------------------------------------------------
// Round-9 structure (kept): ONE WAVE = TWO SAMPLES; lane (s,u) owns all four
// gates of unit u for sample s; 128 weight floats/lane in persistent regs
// v96..v223 (preloaded once; every asm block clobbers the range).
// Round-10 deltas (idle-attack; issue is already at the FP32 MAC floor):
//  (1) x prefetched INSIDE the asm block: global_load at block start,
//      vmcnt(0)+ds_write at block end -> ~900-cyc HBM latency hidden.
//  (2) co-resident-block anti-phase stagger (s_sleep once) so the two
//      waves/SIMD cover each other's LDS/trans stalls instead of stalling
//      in lockstep.
//  (3) accIF finishes before accGO's tail; sigma(i),sigma(f) exps issue
//      under the GO MACs. Same ops, same per-value order -> bitwise output.
// Register map: v64..79 h-quads | v80:81 accIF | v82:83 accGO | v84:85 x |
// v86..92 act temps | v93 x-prefetch | v96+2j (wi,wf)[j] | v160+2j (wg,wo)[j].
// ---------------------------------------------------------------------------

#define PKP(IFE, IFO, GOE, GOO, HP) \
  "v_pk_fma_f32 v[80:81], v[" IFE "], v[" HP "], v[80:81] op_sel_hi:[1,0,1]\n\t" \
  "v_pk_fma_f32 v[82:83], v[" GOE "], v[" HP "], v[82:83] op_sel_hi:[1,0,1]\n\t" \
  "v_pk_fma_f32 v[80:81], v[" IFO "], v[" HP "], v[80:81] op_sel:[0,1,0] op_sel_hi:[1,1,1]\n\t" \
  "v_pk_fma_f32 v[82:83], v[" GOO "], v[" HP "], v[82:83] op_sel:[0,1,0] op_sel_hi:[1,1,1]\n\t"

// IF-only / GO-only pk pairs for the reordered tail.
#define PKIF(E, O, HP) \
  "v_pk_fma_f32 v[80:81], v[" E "], v[" HP "], v[80:81] op_sel_hi:[1,0,1]\n\t" \
  "v_pk_fma_f32 v[80:81], v[" O "], v[" HP "], v[80:81] op_sel:[0,1,0] op_sel_hi:[1,1,1]\n\t"
#define PKGO(E, O, HP) \
  "v_pk_fma_f32 v[82:83], v[" E "], v[" HP "], v[82:83] op_sel_hi:[1,0,1]\n\t" \
  "v_pk_fma_f32 v[82:83], v[" O "], v[" HP "], v[82:83] op_sel:[0,1,0] op_sel_hi:[1,1,1]\n\t"

#define STEP(TT) \
  "ds_read2_b32 v[84:85], %[xa] offset0:" TT " offset1:" TT "\n\t" \
  "ds_read_b128 v[64:67], %[hr] offset:0\n\t" \
  "ds_read_b128 v[68:71], %[hr] offset:16\n\t" \
  "ds_read_b128 v[72:75], %[hr] offset:32\n\t" \
  "ds_read_b128 v[76:79], %[hr] offset:48\n\t" \
  "s_waitcnt lgkmcnt(4)\n\t" \
  "v_pk_fma_f32 v[80:81], %[uvIF], v[84:85], %[bvIF]\n\t" \
  "v_pk_fma_f32 v[82:83], %[uvGO], v[84:85], %[bvGO]\n\t" \
  "s_waitcnt lgkmcnt(3)\n\t" \
  PKP("96:97","98:99","160:161","162:163","64:65") \
  PKP("100:101","102:103","164:165","166:167","66:67") \
  "ds_read_b128 v[64:67], %[hr] offset:64\n\t" \
  "s_waitcnt lgkmcnt(3)\n\t" \
  PKP("104:105","106:107","168:169","170:171","68:69") \
  PKP("108:109","110:111","172:173","174:175","70:71") \
  "ds_read_b128 v[68:71], %[hr] offset:80\n\t" \
  "s_waitcnt lgkmcnt(3)\n\t" \
  PKP("112:113","114:115","176:177","178:179","72:73") \
  PKP("116:117","118:119","180:181","182:183","74:75") \
  "ds_read_b128 v[72:75], %[hr] offset:96\n\t" \
  "s_waitcnt lgkmcnt(3)\n\t" \
  PKP("120:121","122:123","184:185","186:187","76:77") \
  PKP("124:125","126:127","188:189","190:191","78:79") \
  "ds_read_b128 v[76:79], %[hr] offset:112\n\t" \
  "s_waitcnt lgkmcnt(3)\n\t" \
  PKP("128:129","130:131","192:193","194:195","64:65") \
  PKP("132:133","134:135","196:197","198:199","66:67") \
  "s_waitcnt lgkmcnt(2)\n\t" \
  PKP("136:137","138:139","200:201","202:203","68:69") \
  PKP("140:141","142:143","204:205","206:207","70:71") \
  "s_waitcnt lgkmcnt(1)\n\t" \
  PKP("144:145","146:147","208:209","210:211","72:73") \
  PKP("148:149","150:151","212:213","214:215","74:75") \
  "s_waitcnt lgkmcnt(0)\n\t" \
  /* --- reordered tail: finish IF, start sigma(i),sigma(f), then GO --- */ \
  PKIF("152:153","154:155","76:77") \
  PKIF("156:157","158:159","78:79") \
  "v_mul_f32 v86, 0xbfb8aa3b, v80\n\t" \
  "v_exp_f32 v86, v86\n\t" \
  "v_mul_f32 v87, 0xbfb8aa3b, v81\n\t" \
  "v_exp_f32 v87, v87\n\t" \
  PKGO("216:217","218:219","76:77") \
  PKGO("220:221","222:223","78:79") \
  "v_mul_f32 v88, 0x4038aa3b, v82\n\t" \
  "v_exp_f32 v88, v88\n\t" \
  "v_mul_f32 v89, 0xbfb8aa3b, v83\n\t" \
  "v_exp_f32 v89, v89\n\t" \
  "v_add_f32 v86, 1.0, v86\n\t" \
  "v_add_f32 v87, 1.0, v87\n\t" \
  "v_add_f32 v88, 1.0, v88\n\t" \
  "v_add_f32 v89, 1.0, v89\n\t" \
  "v_rcp_f32 v86, v86\n\t" \
  "v_rcp_f32 v87, v87\n\t" \
  "v_rcp_f32 v88, v88\n\t" \
  "v_rcp_f32 v89, v89\n\t" \
  "s_nop 1\n\t" \
  "v_fma_f32 v90, -2.0, v88, 1.0\n\t" \
  "v_mul_f32 v91, v86, v90\n\t" \
  "v_fma_f32 %[c], v87, %[c], v91\n\t" \
  "v_mul_f32 v92, 0x4038aa3b, %[c]\n\t" \
  "v_exp_f32 v92, v92\n\t" \
  "s_nop 1\n\t" \
  "v_add_f32 v92, 1.0, v92\n\t" \
  "v_rcp_f32 v92, v92\n\t" \
  "s_nop 1\n\t" \
  "v_fma_f32 v92, -2.0, v92, 1.0\n\t" \
  "v_mul_f32 %[h], v89, v92\n\t" \
  "ds_write_b32 %[hw], %[h]\n\t"

#define CLOBS \
  "v64","v65","v66","v67","v68","v69","v70","v71","v72","v73","v74","v75", \
  "v76","v77","v78","v79","v80","v81","v82","v83","v84","v85","v86","v87", \
  "v88","v89","v90","v91","v92","v93","v94","v95","v96","v97","v98","v99", \
  "v100","v101","v102","v103","v104","v105","v106","v107","v108","v109", \
  "v110","v111","v112","v113","v114","v115","v116","v117","v118","v119", \
  "v120","v121","v122","v123","v124","v125","v126","v127","v128","v129", \
  "v130","v131","v132","v133","v134","v135","v136","v137","v138","v139", \
  "v140","v141","v142","v143","v144","v145","v146","v147","v148","v149", \
  "v150","v151","v152","v153","v154","v155","v156","v157","v158","v159", \
  "v160","v161","v162","v163","v164","v165","v166","v167","v168","v169", \
  "v170","v171","v172","v173","v174","v175","v176","v177","v178","v179", \
  "v180","v181","v182","v183","v184","v185","v186","v187","v188","v189", \
  "v190","v191","v192","v193","v194","v195","v196","v197","v198","v199", \
  "v200","v201","v202","v203","v204","v205","v206","v207","v208","v209", \
  "v210","v211","v212","v213","v214","v215","v216","v217","v218","v219", \
  "v220","v221","v222","v223"

__global__ __launch_bounds__(BLOCK)
void lstm_fused_kernel(
    const float* __restrict__ x,       // [B, T, 1]
    const float* __restrict__ W_ih,    // [4H, 1]
    const float* __restrict__ W_hh,    // [4H, H] row-major
    const float* __restrict__ b_ih,    // [4H]
    const float* __restrict__ b_hh,    // [4H]
    const float* __restrict__ W_head,  // [1, H]
    const float* __restrict__ b_head,  // [1]
    float* __restrict__ out)           // [B, 1]
{
    __shared__ __align__(16) v2f WIFL[32][34];
    __shared__ __align__(16) v2f WGOL[32][34];
    __shared__ __align__(16) float Hbuf[WAVES_PER_BLOCK][2][32];
    __shared__ __align__(16) float Xbuf[WAVES_PER_BLOCK][2][32];

    const int tid = threadIdx.x;
    for (int idx = tid; idx < 1024; idx += BLOCK) {
        const int u = idx >> 5;
        const int j = idx & 31;
        WIFL[u][j] = (v2f){ W_hh[u * 32 + j],        W_hh[(32 + u) * 32 + j] };
        WGOL[u][j] = (v2f){ W_hh[(64 + u) * 32 + j], W_hh[(96 + u) * 32 + j] };
    }
    __syncthreads();

    const int lane = tid & 63;
    const int u    = lane & 31;
    const int s    = lane >> 5;
    const int wid  = tid >> 6;
    const int b0   = 2 * (blockIdx.x * WAVES_PER_BLOCK + wid);

    // Preload all 64 weight pairs into persistent regs v96..v223 (once).
    {
        const unsigned aIF = (unsigned)(size_t)&WIFL[u][0];
        const unsigned aGO = (unsigned)(size_t)&WGOL[u][0];
        asm volatile(
            "ds_read_b128 v[96:99],   %[wa] offset:0\n\t"
            "ds_read_b128 v[100:103], %[wa] offset:16\n\t"
            "ds_read_b128 v[104:107], %[wa] offset:32\n\t"
            "ds_read_b128 v[108:111], %[wa] offset:48\n\t"
            "ds_read_b128 v[112:115], %[wa] offset:64\n\t"
            "ds_read_b128 v[116:119], %[wa] offset:80\n\t"
            "ds_read_b128 v[120:123], %[wa] offset:96\n\t"
            "ds_read_b128 v[124:127], %[wa] offset:112\n\t"
            "ds_read_b128 v[128:131], %[wa] offset:128\n\t"
            "ds_read_b128 v[132:135], %[wa] offset:144\n\t"
            "ds_read_b128 v[136:139], %[wa] offset:160\n\t"
            "ds_read_b128 v[140:143], %[wa] offset:176\n\t"
            "ds_read_b128 v[144:147], %[wa] offset:192\n\t"
            "ds_read_b128 v[148:151], %[wa] offset:208\n\t"
            "ds_read_b128 v[152:155], %[wa] offset:224\n\t"
            "ds_read_b128 v[156:159], %[wa] offset:240\n\t"
            "ds_read_b128 v[160:163], %[wb] offset:0\n\t"
            "ds_read_b128 v[164:167], %[wb] offset:16\n\t"
            "ds_read_b128 v[168:171], %[wb] offset:32\n\t"
            "ds_read_b128 v[172:175], %[wb] offset:48\n\t"
            "ds_read_b128 v[176:179], %[wb] offset:64\n\t"
            "ds_read_b128 v[180:183], %[wb] offset:80\n\t"
            "ds_read_b128 v[184:187], %[wb] offset:96\n\t"
            "ds_read_b128 v[188:191], %[wb] offset:112\n\t"
            "ds_read_b128 v[192:195], %[wb] offset:128\n\t"
            "ds_read_b128 v[196:199], %[wb] offset:144\n\t"
            "ds_read_b128 v[200:203], %[wb] offset:160\n\t"
            "ds_read_b128 v[204:207], %[wb] offset:176\n\t"
            "ds_read_b128 v[208:211], %[wb] offset:192\n\t"
            "ds_read_b128 v[212:215], %[wb] offset:208\n\t"
            "ds_read_b128 v[216:219], %[wb] offset:224\n\t"
            "ds_read_b128 v[220:223], %[wb] offset:240\n\t"
            "s_waitcnt lgkmcnt(0)"
            :
            : [wa]"v"(aIF), [wb]"v"(aGO)
            : "memory", CLOBS);
    }

    const v2f bvIF = { b_ih[u]      + b_hh[u],      b_ih[32 + u] + b_hh[32 + u] };
    const v2f bvGO = { b_ih[64 + u] + b_hh[64 + u], b_ih[96 + u] + b_hh[96 + u] };
    const v2f uvIF = { W_ih[u],      W_ih[32 + u] };
    const v2f uvGO = { W_ih[64 + u], W_ih[96 + u] };

    const unsigned hr = (unsigned)(size_t)&Hbuf[wid][s][0];
    const unsigned hw = hr + (unsigned)(u * 4);
    const unsigned xa = (unsigned)(size_t)&Xbuf[wid][s][0];
    const unsigned xw = xa + (unsigned)(u * 4);

    const float* xb = x + (size_t)(b0 + s) * SEQ;   // this lane's sample, I==1

    float h = 0.0f, c = 0.0f;
    Hbuf[wid][s][u] = 0.0f;         // h(0)
    Xbuf[wid][s][u] = xb[u];        // x chunk 0 (same-wave LDS in-order)

    // Anti-phase stagger: offset this block ~640 cyc vs its likely CU
    // co-resident (pairing stride 8 or 256 -> parity of bit3 ^ bit8) so the
    // two waves/SIMD cover each other's stalls instead of idling in lockstep.
    if (((blockIdx.x >> 3) ^ (blockIdx.x >> 8)) & 1)
        __builtin_amdgcn_s_sleep(10);

#pragma unroll 1
    for (int t0 = 0; t0 < SEQ; t0 += 32) {
        // Next x chunk address (wraps to chunk 0 on the last iteration: the
        // wrapped load is in-bounds and its Xbuf write is never read).
        const int tn = (t0 + 32) & (SEQ - 1);
        const float* nxt = xb + tn + u;
        asm volatile(
            "global_load_dword v93, %[nx], off\n\t"   // prefetch next x chunk
            STEP("0")  STEP("1")  STEP("2")  STEP("3")
            STEP("4")  STEP("5")  STEP("6")  STEP("7")
            STEP("8")  STEP("9")  STEP("10") STEP("11")
            STEP("12") STEP("13") STEP("14") STEP("15")
            STEP("16") STEP("17") STEP("18") STEP("19")
            STEP("20") STEP("21") STEP("22") STEP("23")
            STEP("24") STEP("25") STEP("26") STEP("27")
            STEP("28") STEP("29") STEP("30") STEP("31")
            "s_waitcnt vmcnt(0)\n\t"                  // ~900cy hidden by 32 steps
            "ds_write_b32 %[xw], v93\n\t"             // stage next chunk
            : [h]"+v"(h), [c]"+v"(c)
            : [hr]"v"(hr), [hw]"v"(hw), [xa]"v"(xa), [xw]"v"(xw),
              [nx]"v"(nxt),
              [uvIF]"v"(uvIF), [bvIF]"v"(bvIF),
              [uvGO]"v"(uvGO), [bvGO]"v"(bvGO)
            : "memory", CLOBS);
    }

    // head: out[b0+s] = sum_u h[u]*W_head[u] + b_head (xor<32 stays per-half)
    float v = h * W_head[u];
#pragma unroll
    for (int off = 16; off >= 1; off >>= 1)
        v += __shfl_xor(v, off);
    if (u == 0) out[b0 + s] = v + b_head[0];
}

extern "C" void kernel_launch(void* const* d_in, const int* in_sizes, int n_in,
                              void* d_out, int out_size, void* d_ws, size_t ws_size,
                              hipStream_t stream) {
    const float* x      = (const float*)d_in[0];
    const float* W_ih   = (const float*)d_in[1];
    const float* W_hh   = (const float*)d_in[2];
    const float* b_ih   = (const float*)d_in[3];
    const float* b_hh   = (const float*)d_in[4];
    const float* W_head = (const float*)d_in[5];
    const float* b_head = (const float*)d_in[6];
    float* out = (float*)d_out;

    const int B = in_sizes[0] / SEQ;                    // 4096
    const int grid = B / (2 * WAVES_PER_BLOCK);         // 512 blocks

    lstm_fused_kernel<<<grid, BLOCK, 0, stream>>>(
        x, W_ih, W_hh, b_ih, b_hh, W_head, b_head, out);
}